// Round 6
// baseline (260.473 us; speedup 1.0000x reference)
//
#include <hip/hip_runtime.h>
#include <hip/hip_bf16.h>

typedef _Float16 f16;
typedef __attribute__((ext_vector_type(8))) _Float16 f16x8;
typedef __attribute__((ext_vector_type(4))) _Float16 f16x4;
typedef __attribute__((ext_vector_type(4))) float f32x4;

#define MFMA16(a, b, c) __builtin_amdgcn_mfma_f32_16x16x32_f16((a), (b), (c), 0, 0, 0)

#define NWIN 4096
#define QKV_ELEMS (NWIN * 8192)  // 33,554,432 f16 per tensor
#define WPB 4                    // windows per attn_proj block (grid 1024 = 1 generation)

// ---------------------------------------------------------------------------
// Weight pre-convert: f32 -> f16 into workspace.
// ---------------------------------------------------------------------------
__global__ void cvt_weights(const float* __restrict__ wq,
                            const float* __restrict__ wp,
                            f16* __restrict__ o) {
    int i = blockIdx.x * blockDim.x + threadIdx.x;
    if (i < 49152) o[i] = (f16)wq[i];
    if (i < 16384) o[49152 + i] = (f16)wp[i];
}

__device__ inline f16x8 cvt8(const float* p) {
    float4 u0 = *(const float4*)p;
    float4 u1 = *(const float4*)(p + 4);
    f16x8 t;
    t[0] = (f16)u0.x; t[1] = (f16)u0.y; t[2] = (f16)u0.z; t[3] = (f16)u0.w;
    t[4] = (f16)u1.x; t[5] = (f16)u1.y; t[6] = (f16)u1.z; t[7] = (f16)u1.w;
    return t;
}

// ---------------------------------------------------------------------------
// Kernel 1: QKV projection. 512 blocks x 8 waves, weights in regs across
// 8 windows x 4 M-tiles. Writes Q plain, K row-major PRE-SWIZZLED (LDS
// image for global_load_lds), V transposed [win][128][64] PLAIN (read as
// B-frags straight from global in kernel 2 — no swizzle on either side).
// ---------------------------------------------------------------------------
__global__ __launch_bounds__(512, 4)
void qkv_gemm(const float* __restrict__ x, const f16* __restrict__ wq_h,
              f16* __restrict__ qws, f16* __restrict__ kws,
              f16* __restrict__ vws) {
    __shared__ f16 xb[2][64 * 128];  // 2 x 16KB, swizzled
    __shared__ f16 tscr[8][320];     // per-wave 16x20 transpose tile

    const int tid = threadIdx.x;
    const int wave = tid >> 6;
    const int lane = tid & 63;
    const int lg = lane >> 4;
    const int lr = lane & 15;
    const int w0 = blockIdx.x * 8;

    const int rdl = lane >> 2;
    const int ra = lane & 3;
    const int rg = 4 * (ra ^ ((rdl >> 2) & 3));

    f16x8 bw[3][4];
#pragma unroll
    for (int j = 0; j < 3; ++j)
#pragma unroll
        for (int kc = 0; kc < 4; ++kc)
            bw[j][kc] = *(const f16x8*)&wq_h[((wave + 8 * j) * 16 + lr) * 128 + kc * 32 + 8 * lg];

    auto stage = [&](int w, int p) {
        const float* xw = x + (size_t)w * (49 * 128);
        for (int i = tid; i < 2048; i += 512) {
            const int row = i >> 5;
            const int c4 = (i & 31) << 2;
            float4 v = {0.f, 0.f, 0.f, 0.f};
            if (row < 49) v = ((const float4*)xw)[i];
            f16x4 t;
            t[0] = (f16)v.x; t[1] = (f16)v.y; t[2] = (f16)v.z; t[3] = (f16)v.w;
            *(f16x4*)&xb[p][row * 128 + (c4 ^ ((row & 7) << 3))] = t;
        }
    };

    stage(w0, 0);
    __syncthreads();

    for (int wi = 0; wi < 8; ++wi) {
        const int w = w0 + wi;
        const int cur = wi & 1;
        if (wi < 7) stage(w + 1, cur ^ 1);

#pragma unroll
        for (int mt = 0; mt < 4; ++mt) {
            const int nb = mt * 16;
            f16x8 a[4];
#pragma unroll
            for (int kc = 0; kc < 4; ++kc)
                a[kc] = *(const f16x8*)&xb[cur][(nb + lr) * 128 + ((kc * 32 + 8 * lg) ^ ((lr & 7) << 3))];

#pragma unroll
            for (int j = 0; j < 3; ++j) {
                f32x4 acc = {0.f, 0.f, 0.f, 0.f};
#pragma unroll
                for (int kc = 0; kc < 4; ++kc) acc = MFMA16(a[kc], bw[j][kc], acc);

                if (j < 2) {
#pragma unroll
                    for (int reg = 0; reg < 4; ++reg)
                        tscr[wave][(4 * lg + reg) * 20 + (lr ^ (4 * lg))] = (f16)acc[reg];
                    f16x4 seg = *(const f16x4*)&tscr[wave][rdl * 20 + rg];
                    const int n = nb + rdl;
                    int col = wave * 16 + 4 * ra;        // local col for Q AND K
                    if (j == 1) col ^= (n & 7) << 3;     // K: pre-swizzle (LDS image)
                    f16* dst = (j == 0) ? qws : kws;
                    *(f16x4*)&dst[(size_t)w * 8192 + n * 128 + col] = seg;
                } else {
#pragma unroll
                    for (int reg = 0; reg < 4; ++reg)
                        tscr[wave][lr * 20 + ((4 * lg + reg) ^ (lr & 12))] = (f16)acc[reg];
                    f16x4 seg = *(const f16x4*)&tscr[wave][rdl * 20 + rg];
                    const int vch = wave * 16 + rdl;
                    const int col = nb + 4 * ra;         // V: PLAIN (reg-read in k2)
                    *(f16x4*)&vws[(size_t)w * 8192 + vch * 64 + col] = seg;
                }
            }
        }
        __syncthreads();
    }
}

// ---------------------------------------------------------------------------
// Kernel 2: attention + output projection. 1024 blocks x 4 waves, WPB=4
// windows each (40KB LDS -> 4 blocks/CU, 1 generation). K double-buffered
// in LDS via global_load_lds with counted vmcnt(4) across raw barriers.
// V^T B-frags loaded global->reg per head (L2/L3-hot, hidden under QK).
// Softmax: unnormalized P written to scr; shfl row-sum runs concurrent
// with PV MFMAs; 1/sum applied to oacc (D row = 4lg+reg matches sum reg).
// ---------------------------------------------------------------------------
__global__ __launch_bounds__(256, 4)
void attn_proj(const f16* __restrict__ qws, const f16* __restrict__ kws,
               const f16* __restrict__ vws, const float* __restrict__ mask,
               const f16* __restrict__ wp_h, const float* __restrict__ bias,
               float* __restrict__ out) {
    __shared__ f16 ks[2][64 * 128];  // 2 x 16KB K double-buffer
    __shared__ f16 scr[4][1024];     // per-wave P/att scratch, 8KB

    const int tid = threadIdx.x;
    const int wave = tid >> 6;
    const int lane = tid & 63;
    const int lg = lane >> 4;
    const int lr = lane & 15;
    const int r0 = wave * 16;
    const int w0 = blockIdx.x * WPB;
    f16* ps = scr[wave];

    auto stageK = [&](int w, int p) {
        const f16* kg = kws + (size_t)w * 8192 + wave * 2048 + lane * 8;
        f16* kl = &ks[p][wave * 2048];
#pragma unroll
        for (int c = 0; c < 4; ++c)
            __builtin_amdgcn_global_load_lds(
                (const __attribute__((address_space(1))) void*)(kg + c * 512),
                (__attribute__((address_space(3))) void*)(kl + c * 512), 16, 0, 0);
    };

    f16x8 aq_c[4], aq_n[4];
    auto loadQ = [&](int w, f16x8* aq) {
#pragma unroll
        for (int h = 0; h < 4; ++h)
            aq[h] = *(const f16x8*)&qws[(size_t)w * 8192 + (r0 + lr) * 128 + h * 32 + 8 * lg];
    };

    // prologue
    loadQ(w0, aq_c);
    stageK(w0, 0);

    const float sc = 0.17677669529663687f;  // 32^-0.5

    for (int t = 0; t < WPB; ++t) {
        const int w = w0 + t;
        const int p = t & 1;

        if (t + 1 < WPB) {
            loadQ(w + 1, aq_n);
            stageK(w + 1, p ^ 1);
            // keep only the 4 stage(t+1) loads in flight; stage(t), Q(t+1),
            // prior stores/mask/V loads all drained.
            asm volatile("s_waitcnt vmcnt(4)" ::: "memory");
        } else {
            asm volatile("s_waitcnt vmcnt(0)" ::: "memory");
        }
        __builtin_amdgcn_s_barrier();       // K(t) visible to all waves
        __builtin_amdgcn_sched_barrier(0);  // no hoisting above the barrier

        // ---------------- compute window w ----------------
        const float* mw = mask + (size_t)(w & 63) * (49 * 49);
        float mv[4][4];
#pragma unroll
        for (int reg = 0; reg < 4; ++reg) {
            const int n = r0 + 4 * lg + reg;
#pragma unroll
            for (int nt = 0; nt < 4; ++nt) {
                const int col = nt * 16 + lr;
                mv[reg][nt] = (n < 49 && col < 49) ? mw[n * 49 + col] : 0.f;
            }
        }

        f32x4 oacc[4][2];
#pragma unroll
        for (int h = 0; h < 4; ++h) {
            // V^T B-frags straight from global (first use after softmax)
            f16x8 bv[2][2];
#pragma unroll
            for (int nt = 0; nt < 2; ++nt)
#pragma unroll
                for (int kc = 0; kc < 2; ++kc) {
                    const int vrow = h * 32 + nt * 16 + lr;
                    bv[nt][kc] = *(const f16x8*)&vws[(size_t)w * 8192 + vrow * 64 + kc * 32 + 8 * lg];
                }

            // QK^T
            f32x4 s[4];
#pragma unroll
            for (int nt = 0; nt < 4; ++nt) {
                const int krow = nt * 16 + lr;
                f16x8 bk = *(const f16x8*)&ks[p][krow * 128 + ((h * 32 + 8 * lg) ^ ((krow & 7) << 3))];
                f32x4 z = {0.f, 0.f, 0.f, 0.f};
                s[nt] = MFMA16(aq_c[h], bk, z);
            }

            // unnormalized softmax numerators -> scr; row-sums kept local
            float lsum[4];
#pragma unroll
            for (int reg = 0; reg < 4; ++reg) {
                const int row = 4 * lg + reg;
                float sum = 0.f;
#pragma unroll
                for (int nt = 0; nt < 4; ++nt) {
                    const int col = nt * 16 + lr;
                    float e = (col < 49) ? __expf(s[nt][reg] * sc + mv[reg][nt]) : 0.f;
                    sum += e;
                    ps[row * 64 + (col ^ ((row & 7) << 3))] = (f16)e;
                }
                lsum[reg] = sum;
            }

            // PV (MFMAs overlap the shfl reduction below)
            f16x8 ap[2];
#pragma unroll
            for (int kc = 0; kc < 2; ++kc)
                ap[kc] = *(const f16x8*)&ps[lr * 64 + ((kc * 32 + 8 * lg) ^ ((lr & 7) << 3))];
            f32x4 acc0 = {0.f, 0.f, 0.f, 0.f};
            f32x4 acc1 = {0.f, 0.f, 0.f, 0.f};
#pragma unroll
            for (int kc = 0; kc < 2; ++kc) {
                acc0 = MFMA16(ap[kc], bv[0][kc], acc0);
                acc1 = MFMA16(ap[kc], bv[1][kc], acc1);
            }

            // row-sum reduce (off the MFMA critical path) + normalize oacc
#pragma unroll
            for (int reg = 0; reg < 4; ++reg) {
                float sum = lsum[reg];
                for (int d = 1; d < 16; d <<= 1) sum += __shfl_xor(sum, d, 64);
                const float inv = __fdividef(1.f, sum);
                acc0[reg] *= inv;
                acc1[reg] *= inv;
            }
            oacc[h][0] = acc0;
            oacc[h][1] = acc1;
        }

        // att D-layout -> proj A-frags via scratch
        f16x8 aa[4];
#pragma unroll
        for (int pass = 0; pass < 2; ++pass) {
#pragma unroll
            for (int h2 = 0; h2 < 2; ++h2)
#pragma unroll
                for (int nt = 0; nt < 2; ++nt)
#pragma unroll
                    for (int reg = 0; reg < 4; ++reg) {
                        const int row = 4 * lg + reg;
                        const int col = h2 * 32 + nt * 16 + lr;
                        ps[row * 64 + (col ^ ((row & 7) << 3))] = (f16)oacc[pass * 2 + h2][nt][reg];
                    }
#pragma unroll
            for (int kcg = 0; kcg < 2; ++kcg)
                aa[pass * 2 + kcg] =
                    *(const f16x8*)&ps[lr * 64 + ((kcg * 32 + 8 * lg) ^ ((lr & 7) << 3))];
        }

        // output projection + bias
        float* ob = out + (size_t)w * (49 * 128);
#pragma unroll
        for (int ct = 0; ct < 8; ++ct) {
            const int wrow = ct * 16 + lr;
            f16x8 bwv[4];
#pragma unroll
            for (int kc = 0; kc < 4; ++kc)
                bwv[kc] = *(const f16x8*)&wp_h[wrow * 128 + kc * 32 + 8 * lg];
            f32x4 acc = {0.f, 0.f, 0.f, 0.f};
#pragma unroll
            for (int kc = 0; kc < 4; ++kc) acc = MFMA16(aa[kc], bwv[kc], acc);

            const float bc = bias[wrow];
#pragma unroll
            for (int reg = 0; reg < 4; ++reg) {
                const int n = r0 + 4 * lg + reg;
                if (n < 49) ob[n * 128 + ct * 16 + lr] = acc[reg] + bc;
            }
        }
        // --------------------------------------------------

        __builtin_amdgcn_s_barrier();  // all waves done reading ks[p]

#pragma unroll
        for (int h = 0; h < 4; ++h) aq_c[h] = aq_n[h];
    }
}

// ---------------------------------------------------------------------------
// Fallback: fused kernel (used when ws too small for the split path).
// ---------------------------------------------------------------------------
template <bool WB>
__global__ __launch_bounds__(256, 4)
void fused_wattn(const float* __restrict__ x, const float* __restrict__ mask,
                 const float* __restrict__ wq_f, const float* __restrict__ wp_f,
                 const f16* __restrict__ wq_h, const f16* __restrict__ wp_h,
                 const float* __restrict__ bias, float* __restrict__ out) {
    __shared__ f16 ks[64 * 128];
    __shared__ f16 vt[128 * 64];
    __shared__ f16 scr[4][1024];

    const int b = blockIdx.x;
    const int wid = b & 63;
    const int tid = threadIdx.x;
    const int wave = tid >> 6;
    const int lane = tid & 63;
    const int lg = lane >> 4;
    const int lr = lane & 15;
    const int r0 = wave * 16;
    f16* ps = scr[wave];

    f16x8 a[4];
    {
        const int xrow = r0 + lr;
        if (xrow < 49) {
            const float* xp = x + ((size_t)b * 49 + xrow) * 128 + 8 * lg;
#pragma unroll
            for (int kc = 0; kc < 4; ++kc) a[kc] = cvt8(xp + kc * 32);
        } else {
            f16x8 z = {0, 0, 0, 0, 0, 0, 0, 0};
#pragma unroll
            for (int kc = 0; kc < 4; ++kc) a[kc] = z;
        }
    }

    float mv[4][4];
#pragma unroll
    for (int reg = 0; reg < 4; ++reg) {
        const int n = r0 + 4 * lg + reg;
#pragma unroll
        for (int nt = 0; nt < 4; ++nt) {
            const int col = nt * 16 + lr;
            mv[reg][nt] = (n < 49 && col < 49) ? mask[((size_t)wid * 49 + n) * 49 + col] : 0.f;
        }
    }

    f16x4 qd[8];
#pragma unroll
    for (int ct = 0; ct < 24; ++ct) {
        const int wrow = ct * 16 + lr;
        f16x8 bw[4];
        if (WB) {
#pragma unroll
            for (int kc = 0; kc < 4; ++kc)
                bw[kc] = *(const f16x8*)&wq_h[wrow * 128 + kc * 32 + 8 * lg];
        } else {
#pragma unroll
            for (int kc = 0; kc < 4; ++kc)
                bw[kc] = cvt8(&wq_f[wrow * 128 + kc * 32 + 8 * lg]);
        }
        f32x4 acc = {0.f, 0.f, 0.f, 0.f};
#pragma unroll
        for (int kc = 0; kc < 4; ++kc) acc = MFMA16(a[kc], bw[kc], acc);

        if (ct < 8) {
            f16x4 q;
#pragma unroll
            for (int reg = 0; reg < 4; ++reg) q[reg] = (f16)acc[reg];
            qd[ct] = q;
        } else if (ct < 16) {
#pragma unroll
            for (int reg = 0; reg < 4; ++reg) {
                const int n = r0 + 4 * lg + reg;
                const int c = wrow - 128;
                ks[n * 128 + (c ^ ((n & 7) << 3))] = (f16)acc[reg];
            }
        } else {
#pragma unroll
            for (int reg = 0; reg < 4; ++reg) {
                const int n = r0 + 4 * lg + reg;
                const int dch = wrow - 256;
                vt[dch * 64 + (n ^ ((dch & 7) << 3))] = (f16)acc[reg];
            }
        }
    }
    __syncthreads();

    const float sc = 0.17677669529663687f;
    f32x4 oacc[4][2];

#pragma unroll
    for (int h = 0; h < 4; ++h) {
#pragma unroll
        for (int c2 = 0; c2 < 2; ++c2)
#pragma unroll
            for (int reg = 0; reg < 4; ++reg) {
                const int row = 4 * lg + reg;
                const int col = c2 * 16 + lr;
                ps[row * 32 + (col ^ ((row & 3) << 3))] = qd[2 * h + c2][reg];
            }
        f16x8 aq = *(const f16x8*)&ps[lr * 32 + ((8 * lg) ^ ((lr & 3) << 3))];

        f32x4 s[4];
#pragma unroll
        for (int nt = 0; nt < 4; ++nt) {
            const int krow = nt * 16 + lr;
            f16x8 bk = *(const f16x8*)&ks[krow * 128 + ((h * 32 + 8 * lg) ^ ((krow & 7) << 3))];
            f32x4 z = {0.f, 0.f, 0.f, 0.f};
            s[nt] = MFMA16(aq, bk, z);
        }

#pragma unroll
        for (int reg = 0; reg < 4; ++reg) {
            float vals[4];
            float sum = 0.f;
#pragma unroll
            for (int nt = 0; nt < 4; ++nt) {
                const int col = nt * 16 + lr;
                float e = (col < 49) ? __expf(s[nt][reg] * sc + mv[reg][nt]) : 0.f;
                vals[nt] = e;
                sum += e;
            }
            for (int d = 1; d < 16; d <<= 1) sum += __shfl_xor(sum, d, 64);
            const float inv = __fdividef(1.f, sum);
            const int row = 4 * lg + reg;
#pragma unroll
            for (int nt = 0; nt < 4; ++nt) {
                const int col = nt * 16 + lr;
                ps[row * 64 + (col ^ ((row & 7) << 3))] = (f16)(vals[nt] * inv);
            }
        }

        f16x8 ap[2];
#pragma unroll
        for (int kc = 0; kc < 2; ++kc)
            ap[kc] = *(const f16x8*)&ps[lr * 64 + ((kc * 32 + 8 * lg) ^ ((lr & 7) << 3))];
#pragma unroll
        for (int nt = 0; nt < 2; ++nt) {
            const int vrow = h * 32 + nt * 16 + lr;
            f32x4 acc = {0.f, 0.f, 0.f, 0.f};
#pragma unroll
            for (int kc = 0; kc < 2; ++kc) {
                f16x8 bv = *(const f16x8*)&vt[vrow * 64 + ((kc * 32 + 8 * lg) ^ ((vrow & 7) << 3))];
                acc = MFMA16(ap[kc], bv, acc);
            }
            oacc[h][nt] = acc;
        }
    }

    f16x8 aa[4];
#pragma unroll
    for (int pass = 0; pass < 2; ++pass) {
#pragma unroll
        for (int h2 = 0; h2 < 2; ++h2)
#pragma unroll
            for (int nt = 0; nt < 2; ++nt)
#pragma unroll
                for (int reg = 0; reg < 4; ++reg) {
                    const int row = 4 * lg + reg;
                    const int col = h2 * 32 + nt * 16 + lr;
                    ps[row * 64 + (col ^ ((row & 7) << 3))] = (f16)oacc[pass * 2 + h2][nt][reg];
                }
#pragma unroll
        for (int kcg = 0; kcg < 2; ++kcg)
            aa[pass * 2 + kcg] = *(const f16x8*)&ps[lr * 64 + ((kcg * 32 + 8 * lg) ^ ((lr & 7) << 3))];
    }

    float* ob = out + (size_t)b * (49 * 128);
#pragma unroll
    for (int ct = 0; ct < 8; ++ct) {
        const int wrow = ct * 16 + lr;
        f16x8 bw[4];
        if (WB) {
#pragma unroll
            for (int kc = 0; kc < 4; ++kc)
                bw[kc] = *(const f16x8*)&wp_h[wrow * 128 + kc * 32 + 8 * lg];
        } else {
#pragma unroll
            for (int kc = 0; kc < 4; ++kc)
                bw[kc] = cvt8(&wp_f[wrow * 128 + kc * 32 + 8 * lg]);
        }
        f32x4 acc = {0.f, 0.f, 0.f, 0.f};
#pragma unroll
        for (int kc = 0; kc < 4; ++kc) acc = MFMA16(aa[kc], bw[kc], acc);

        const float bc = bias[wrow];
#pragma unroll
        for (int reg = 0; reg < 4; ++reg) {
            const int n = r0 + 4 * lg + reg;
            if (n < 49) ob[n * 128 + ct * 16 + lr] = acc[reg] + bc;
        }
    }
}

extern "C" void kernel_launch(void* const* d_in, const int* in_sizes, int n_in,
                              void* d_out, int out_size, void* d_ws, size_t ws_size,
                              hipStream_t stream) {
    const float* x = (const float*)d_in[0];
    const float* mask = (const float*)d_in[1];
    const float* wq = (const float*)d_in[2];
    const float* wp = (const float*)d_in[3];
    const float* bp = (const float*)d_in[4];
    float* out = (float*)d_out;

    const size_t need_split = (size_t)(65536 + 3 * QKV_ELEMS) * sizeof(f16);
    const size_t need_wb = (size_t)(49152 + 16384) * sizeof(f16);

    if (ws_size >= need_split && d_ws != nullptr) {
        f16* wsh = (f16*)d_ws;
        f16* wq_h = wsh;
        f16* wp_h = wsh + 49152;
        f16* qws = wsh + 65536;
        f16* kws = qws + QKV_ELEMS;
        f16* vws = kws + QKV_ELEMS;
        cvt_weights<<<192, 256, 0, stream>>>(wq, wp, wsh);
        qkv_gemm<<<512, 512, 0, stream>>>(x, wq_h, qws, kws, vws);
        attn_proj<<<NWIN / WPB, 256, 0, stream>>>(qws, kws, vws, mask, wp_h, bp, out);
    } else if (ws_size >= need_wb && d_ws != nullptr) {
        f16* wsh = (f16*)d_ws;
        cvt_weights<<<192, 256, 0, stream>>>(wq, wp, wsh);
        fused_wattn<true><<<4096, 256, 0, stream>>>(x, mask, wq, wp, wsh, wsh + 49152, bp, out);
    } else {
        fused_wattn<false><<<4096, 256, 0, stream>>>(x, mask, wq, wp, nullptr, nullptr, bp, out);
    }
}

// Round 7
// 221.714 us; speedup vs baseline: 1.1748x; 1.1748x over previous
//
#include <hip/hip_runtime.h>
#include <hip/hip_bf16.h>

typedef _Float16 f16;
typedef __attribute__((ext_vector_type(8))) _Float16 f16x8;
typedef __attribute__((ext_vector_type(4))) _Float16 f16x4;
typedef __attribute__((ext_vector_type(4))) float f32x4;

#define MFMA16(a, b, c) __builtin_amdgcn_mfma_f32_16x16x32_f16((a), (b), (c), 0, 0, 0)

#define NWIN 4096
#define QKV_ELEMS (NWIN * 8192)  // 33,554,432 f16 per tensor

// ---------------------------------------------------------------------------
// Weight pre-convert: f32 -> f16 into workspace.
// ---------------------------------------------------------------------------
__global__ void cvt_weights(const float* __restrict__ wq,
                            const float* __restrict__ wp,
                            f16* __restrict__ o) {
    int i = blockIdx.x * blockDim.x + threadIdx.x;
    if (i < 49152) o[i] = (f16)wq[i];
    if (i < 16384) o[49152 + i] = (f16)wp[i];
}

__device__ inline f16x8 cvt8(const float* p) {
    float4 u0 = *(const float4*)p;
    float4 u1 = *(const float4*)(p + 4);
    f16x8 t;
    t[0] = (f16)u0.x; t[1] = (f16)u0.y; t[2] = (f16)u0.z; t[3] = (f16)u0.w;
    t[4] = (f16)u1.x; t[5] = (f16)u1.y; t[6] = (f16)u1.z; t[7] = (f16)u1.w;
    return t;
}

// ---------------------------------------------------------------------------
// Kernel 1: QKV projection. 512 blocks x 8 waves, weights in regs across
// 8 windows x 4 M-tiles. Writes Q, K row-major PLAIN [win][64][128] and
// V transposed PLAIN [win][128][64] — kernel 2 reads all three as B-frags
// straight from global (no swizzle on either side).
// ---------------------------------------------------------------------------
__global__ __launch_bounds__(512, 4)
void qkv_gemm(const float* __restrict__ x, const f16* __restrict__ wq_h,
              f16* __restrict__ qws, f16* __restrict__ kws,
              f16* __restrict__ vws) {
    __shared__ f16 xb[2][64 * 128];  // 2 x 16KB, swizzled
    __shared__ f16 tscr[8][320];     // per-wave 16x20 transpose tile

    const int tid = threadIdx.x;
    const int wave = tid >> 6;
    const int lane = tid & 63;
    const int lg = lane >> 4;
    const int lr = lane & 15;
    const int w0 = blockIdx.x * 8;

    const int rdl = lane >> 2;
    const int ra = lane & 3;
    const int rg = 4 * (ra ^ ((rdl >> 2) & 3));

    f16x8 bw[3][4];
#pragma unroll
    for (int j = 0; j < 3; ++j)
#pragma unroll
        for (int kc = 0; kc < 4; ++kc)
            bw[j][kc] = *(const f16x8*)&wq_h[((wave + 8 * j) * 16 + lr) * 128 + kc * 32 + 8 * lg];

    auto stage = [&](int w, int p) {
        const float* xw = x + (size_t)w * (49 * 128);
        for (int i = tid; i < 2048; i += 512) {
            const int row = i >> 5;
            const int c4 = (i & 31) << 2;
            float4 v = {0.f, 0.f, 0.f, 0.f};
            if (row < 49) v = ((const float4*)xw)[i];
            f16x4 t;
            t[0] = (f16)v.x; t[1] = (f16)v.y; t[2] = (f16)v.z; t[3] = (f16)v.w;
            *(f16x4*)&xb[p][row * 128 + (c4 ^ ((row & 7) << 3))] = t;
        }
    };

    stage(w0, 0);
    __syncthreads();

    for (int wi = 0; wi < 8; ++wi) {
        const int w = w0 + wi;
        const int cur = wi & 1;
        if (wi < 7) stage(w + 1, cur ^ 1);

#pragma unroll
        for (int mt = 0; mt < 4; ++mt) {
            const int nb = mt * 16;
            f16x8 a[4];
#pragma unroll
            for (int kc = 0; kc < 4; ++kc)
                a[kc] = *(const f16x8*)&xb[cur][(nb + lr) * 128 + ((kc * 32 + 8 * lg) ^ ((lr & 7) << 3))];

#pragma unroll
            for (int j = 0; j < 3; ++j) {
                f32x4 acc = {0.f, 0.f, 0.f, 0.f};
#pragma unroll
                for (int kc = 0; kc < 4; ++kc) acc = MFMA16(a[kc], bw[j][kc], acc);

                if (j < 2) {
#pragma unroll
                    for (int reg = 0; reg < 4; ++reg)
                        tscr[wave][(4 * lg + reg) * 20 + (lr ^ (4 * lg))] = (f16)acc[reg];
                    f16x4 seg = *(const f16x4*)&tscr[wave][rdl * 20 + rg];
                    const int n = nb + rdl;
                    const int col = wave * 16 + 4 * ra;  // local col for Q AND K, PLAIN
                    f16* dst = (j == 0) ? qws : kws;
                    *(f16x4*)&dst[(size_t)w * 8192 + n * 128 + col] = seg;
                } else {
#pragma unroll
                    for (int reg = 0; reg < 4; ++reg)
                        tscr[wave][lr * 20 + ((4 * lg + reg) ^ (lr & 12))] = (f16)acc[reg];
                    f16x4 seg = *(const f16x4*)&tscr[wave][rdl * 20 + rg];
                    const int vch = wave * 16 + rdl;
                    const int col = nb + 4 * ra;         // V: PLAIN
                    *(f16x4*)&vws[(size_t)w * 8192 + vch * 64 + col] = seg;
                }
            }
        }
        __syncthreads();
    }
}

// ---------------------------------------------------------------------------
// Kernel 2: attention + output projection, BARRIER-FREE. 4096 blocks x 4
// waves, one window per block. Q/K/V all read as fragments straight from
// global (plain layouts, L2/MALL-hot; sibling waves share via XCD L2).
// LDS = 8KB per-wave P/att scratch only -> occupancy is VGPR-bound.
// Softmax: unnormalized P -> scr; shfl row-sum overlaps PV MFMAs; 1/sum
// applied to oacc afterwards. No __syncthreads anywhere.
// ---------------------------------------------------------------------------
__global__ __launch_bounds__(256, 4)
void attn_proj(const f16* __restrict__ qws, const f16* __restrict__ kws,
               const f16* __restrict__ vws, const float* __restrict__ mask,
               const f16* __restrict__ wp_h, const float* __restrict__ bias,
               float* __restrict__ out) {
    __shared__ f16 scr[4][1024];  // per-wave scratch, 8KB total

    const int b = blockIdx.x;
    const int wid = b & 63;
    const int tid = threadIdx.x;
    const int wave = tid >> 6;
    const int lane = tid & 63;
    const int lg = lane >> 4;
    const int lr = lane & 15;
    const int r0 = wave * 16;
    f16* ps = scr[wave];

    // ---- mask first (deepest prefetch; scalar but L2/L3-hot) ----
    const float* mw = mask + (size_t)wid * (49 * 49);
    float mv[4][4];
#pragma unroll
    for (int reg = 0; reg < 4; ++reg) {
        const int n = r0 + 4 * lg + reg;
#pragma unroll
        for (int nt = 0; nt < 4; ++nt) {
            const int col = nt * 16 + lr;
            mv[reg][nt] = (n < 49 && col < 49) ? mw[n * 49 + col] : 0.f;
        }
    }

    // ---- Q fragments ----
    f16x8 aq[4];
#pragma unroll
    for (int h = 0; h < 4; ++h)
        aq[h] = *(const f16x8*)&qws[(size_t)b * 8192 + (r0 + lr) * 128 + h * 32 + 8 * lg];

    const f16* kb = kws + (size_t)b * 8192;
    const f16* vb = vws + (size_t)b * 8192;

    const float sc = 0.17677669529663687f;  // 32^-0.5
    f32x4 oacc[4][2];

#pragma unroll
    for (int h = 0; h < 4; ++h) {
        // K B-frags straight from global (plain row-major)
        f16x8 bk[4];
#pragma unroll
        for (int nt = 0; nt < 4; ++nt)
            bk[nt] = *(const f16x8*)&kb[(nt * 16 + lr) * 128 + h * 32 + 8 * lg];
        // V^T B-frags straight from global (plain)
        f16x8 bv[2][2];
#pragma unroll
        for (int nt = 0; nt < 2; ++nt)
#pragma unroll
            for (int kc = 0; kc < 2; ++kc)
                bv[nt][kc] = *(const f16x8*)&vb[(h * 32 + nt * 16 + lr) * 64 + kc * 32 + 8 * lg];

        // QK^T
        __builtin_amdgcn_s_setprio(1);
        f32x4 s[4];
#pragma unroll
        for (int nt = 0; nt < 4; ++nt) {
            f32x4 z = {0.f, 0.f, 0.f, 0.f};
            s[nt] = MFMA16(aq[h], bk[nt], z);
        }
        __builtin_amdgcn_s_setprio(0);

        // unnormalized softmax numerators -> scr; row-sums kept local
        float lsum[4];
#pragma unroll
        for (int reg = 0; reg < 4; ++reg) {
            const int row = 4 * lg + reg;
            float sum = 0.f;
#pragma unroll
            for (int nt = 0; nt < 4; ++nt) {
                const int col = nt * 16 + lr;
                float e = (col < 49) ? __expf(s[nt][reg] * sc + mv[reg][nt]) : 0.f;
                sum += e;
                ps[row * 64 + (col ^ ((row & 7) << 3))] = (f16)e;
            }
            lsum[reg] = sum;
        }

        // PV (MFMAs overlap the shfl reduction below)
        f16x8 ap[2];
#pragma unroll
        for (int kc = 0; kc < 2; ++kc)
            ap[kc] = *(const f16x8*)&ps[lr * 64 + ((kc * 32 + 8 * lg) ^ ((lr & 7) << 3))];
        __builtin_amdgcn_s_setprio(1);
        f32x4 acc0 = {0.f, 0.f, 0.f, 0.f};
        f32x4 acc1 = {0.f, 0.f, 0.f, 0.f};
#pragma unroll
        for (int kc = 0; kc < 2; ++kc) {
            acc0 = MFMA16(ap[kc], bv[0][kc], acc0);
            acc1 = MFMA16(ap[kc], bv[1][kc], acc1);
        }
        __builtin_amdgcn_s_setprio(0);

        // row-sum reduce (off the MFMA critical path) + normalize
#pragma unroll
        for (int reg = 0; reg < 4; ++reg) {
            float sum = lsum[reg];
            for (int d = 1; d < 16; d <<= 1) sum += __shfl_xor(sum, d, 64);
            const float inv = __fdividef(1.f, sum);
            acc0[reg] *= inv;
            acc1[reg] *= inv;
        }
        oacc[h][0] = acc0;
        oacc[h][1] = acc1;
    }

    // ---- att D-layout -> proj A-frags via per-wave scratch ----
    f16x8 aa[4];
#pragma unroll
    for (int pass = 0; pass < 2; ++pass) {
#pragma unroll
        for (int h2 = 0; h2 < 2; ++h2)
#pragma unroll
            for (int nt = 0; nt < 2; ++nt)
#pragma unroll
                for (int reg = 0; reg < 4; ++reg) {
                    const int row = 4 * lg + reg;
                    const int col = h2 * 32 + nt * 16 + lr;
                    ps[row * 64 + (col ^ ((row & 7) << 3))] = (f16)oacc[pass * 2 + h2][nt][reg];
                }
#pragma unroll
        for (int kcg = 0; kcg < 2; ++kcg)
            aa[pass * 2 + kcg] =
                *(const f16x8*)&ps[lr * 64 + ((kcg * 32 + 8 * lg) ^ ((lr & 7) << 3))];
    }

    // ---- output projection + bias, depth-2 weight pipeline ----
    float* ob = out + (size_t)b * (49 * 128);
    f16x8 bwv[2][4];
#pragma unroll
    for (int kc = 0; kc < 4; ++kc)
        bwv[0][kc] = *(const f16x8*)&wp_h[(0 * 16 + lr) * 128 + kc * 32 + 8 * lg];
#pragma unroll
    for (int ct = 0; ct < 8; ++ct) {
        const int cur = ct & 1;
        if (ct < 7) {
#pragma unroll
            for (int kc = 0; kc < 4; ++kc)
                bwv[cur ^ 1][kc] =
                    *(const f16x8*)&wp_h[((ct + 1) * 16 + lr) * 128 + kc * 32 + 8 * lg];
        }
        __builtin_amdgcn_s_setprio(1);
        f32x4 acc = {0.f, 0.f, 0.f, 0.f};
#pragma unroll
        for (int kc = 0; kc < 4; ++kc) acc = MFMA16(aa[kc], bwv[cur][kc], acc);
        __builtin_amdgcn_s_setprio(0);

        const float bc = bias[ct * 16 + lr];
#pragma unroll
        for (int reg = 0; reg < 4; ++reg) {
            const int n = r0 + 4 * lg + reg;
            if (n < 49) ob[n * 128 + ct * 16 + lr] = acc[reg] + bc;
        }
    }
}

// ---------------------------------------------------------------------------
// Fallback: fused kernel (used when ws too small for the split path).
// ---------------------------------------------------------------------------
template <bool WB>
__global__ __launch_bounds__(256, 4)
void fused_wattn(const float* __restrict__ x, const float* __restrict__ mask,
                 const float* __restrict__ wq_f, const float* __restrict__ wp_f,
                 const f16* __restrict__ wq_h, const f16* __restrict__ wp_h,
                 const float* __restrict__ bias, float* __restrict__ out) {
    __shared__ f16 ks[64 * 128];
    __shared__ f16 vt[128 * 64];
    __shared__ f16 scr[4][1024];

    const int b = blockIdx.x;
    const int wid = b & 63;
    const int tid = threadIdx.x;
    const int wave = tid >> 6;
    const int lane = tid & 63;
    const int lg = lane >> 4;
    const int lr = lane & 15;
    const int r0 = wave * 16;
    f16* ps = scr[wave];

    f16x8 a[4];
    {
        const int xrow = r0 + lr;
        if (xrow < 49) {
            const float* xp = x + ((size_t)b * 49 + xrow) * 128 + 8 * lg;
#pragma unroll
            for (int kc = 0; kc < 4; ++kc) a[kc] = cvt8(xp + kc * 32);
        } else {
            f16x8 z = {0, 0, 0, 0, 0, 0, 0, 0};
#pragma unroll
            for (int kc = 0; kc < 4; ++kc) a[kc] = z;
        }
    }

    float mv[4][4];
#pragma unroll
    for (int reg = 0; reg < 4; ++reg) {
        const int n = r0 + 4 * lg + reg;
#pragma unroll
        for (int nt = 0; nt < 4; ++nt) {
            const int col = nt * 16 + lr;
            mv[reg][nt] = (n < 49 && col < 49) ? mask[((size_t)wid * 49 + n) * 49 + col] : 0.f;
        }
    }

    f16x4 qd[8];
#pragma unroll
    for (int ct = 0; ct < 24; ++ct) {
        const int wrow = ct * 16 + lr;
        f16x8 bw[4];
        if (WB) {
#pragma unroll
            for (int kc = 0; kc < 4; ++kc)
                bw[kc] = *(const f16x8*)&wq_h[wrow * 128 + kc * 32 + 8 * lg];
        } else {
#pragma unroll
            for (int kc = 0; kc < 4; ++kc)
                bw[kc] = cvt8(&wq_f[wrow * 128 + kc * 32 + 8 * lg]);
        }
        f32x4 acc = {0.f, 0.f, 0.f, 0.f};
#pragma unroll
        for (int kc = 0; kc < 4; ++kc) acc = MFMA16(a[kc], bw[kc], acc);

        if (ct < 8) {
            f16x4 q;
#pragma unroll
            for (int reg = 0; reg < 4; ++reg) q[reg] = (f16)acc[reg];
            qd[ct] = q;
        } else if (ct < 16) {
#pragma unroll
            for (int reg = 0; reg < 4; ++reg) {
                const int n = r0 + 4 * lg + reg;
                const int c = wrow - 128;
                ks[n * 128 + (c ^ ((n & 7) << 3))] = (f16)acc[reg];
            }
        } else {
#pragma unroll
            for (int reg = 0; reg < 4; ++reg) {
                const int n = r0 + 4 * lg + reg;
                const int dch = wrow - 256;
                vt[dch * 64 + (n ^ ((dch & 7) << 3))] = (f16)acc[reg];
            }
        }
    }
    __syncthreads();

    const float sc = 0.17677669529663687f;
    f32x4 oacc[4][2];

#pragma unroll
    for (int h = 0; h < 4; ++h) {
#pragma unroll
        for (int c2 = 0; c2 < 2; ++c2)
#pragma unroll
            for (int reg = 0; reg < 4; ++reg) {
                const int row = 4 * lg + reg;
                const int col = c2 * 16 + lr;
                ps[row * 32 + (col ^ ((row & 3) << 3))] = qd[2 * h + c2][reg];
            }
        f16x8 aq = *(const f16x8*)&ps[lr * 32 + ((8 * lg) ^ ((lr & 3) << 3))];

        f32x4 s[4];
#pragma unroll
        for (int nt = 0; nt < 4; ++nt) {
            const int krow = nt * 16 + lr;
            f16x8 bk = *(const f16x8*)&ks[krow * 128 + ((h * 32 + 8 * lg) ^ ((krow & 7) << 3))];
            f32x4 z = {0.f, 0.f, 0.f, 0.f};
            s[nt] = MFMA16(aq, bk, z);
        }

#pragma unroll
        for (int reg = 0; reg < 4; ++reg) {
            float vals[4];
            float sum = 0.f;
#pragma unroll
            for (int nt = 0; nt < 4; ++nt) {
                const int col = nt * 16 + lr;
                float e = (col < 49) ? __expf(s[nt][reg] * sc + mv[reg][nt]) : 0.f;
                vals[nt] = e;
                sum += e;
            }
            for (int d = 1; d < 16; d <<= 1) sum += __shfl_xor(sum, d, 64);
            const float inv = __fdividef(1.f, sum);
            const int row = 4 * lg + reg;
#pragma unroll
            for (int nt = 0; nt < 4; ++nt) {
                const int col = nt * 16 + lr;
                ps[row * 64 + (col ^ ((row & 7) << 3))] = (f16)(vals[nt] * inv);
            }
        }

        f16x8 ap[2];
#pragma unroll
        for (int kc = 0; kc < 2; ++kc)
            ap[kc] = *(const f16x8*)&ps[lr * 64 + ((kc * 32 + 8 * lg) ^ ((lr & 7) << 3))];
#pragma unroll
        for (int nt = 0; nt < 2; ++nt) {
            const int vrow = h * 32 + nt * 16 + lr;
            f32x4 acc = {0.f, 0.f, 0.f, 0.f};
#pragma unroll
            for (int kc = 0; kc < 2; ++kc) {
                f16x8 bv = *(const f16x8*)&vt[vrow * 64 + ((kc * 32 + 8 * lg) ^ ((vrow & 7) << 3))];
                acc = MFMA16(ap[kc], bv, acc);
            }
            oacc[h][nt] = acc;
        }
    }

    f16x8 aa[4];
#pragma unroll
    for (int pass = 0; pass < 2; ++pass) {
#pragma unroll
        for (int h2 = 0; h2 < 2; ++h2)
#pragma unroll
            for (int nt = 0; nt < 2; ++nt)
#pragma unroll
                for (int reg = 0; reg < 4; ++reg) {
                    const int row = 4 * lg + reg;
                    const int col = h2 * 32 + nt * 16 + lr;
                    ps[row * 64 + (col ^ ((row & 7) << 3))] = (f16)oacc[pass * 2 + h2][nt][reg];
                }
#pragma unroll
        for (int kcg = 0; kcg < 2; ++kcg)
            aa[pass * 2 + kcg] = *(const f16x8*)&ps[lr * 64 + ((kcg * 32 + 8 * lg) ^ ((lr & 7) << 3))];
    }

    float* ob = out + (size_t)b * (49 * 128);
#pragma unroll
    for (int ct = 0; ct < 8; ++ct) {
        const int wrow = ct * 16 + lr;
        f16x8 bw[4];
        if (WB) {
#pragma unroll
            for (int kc = 0; kc < 4; ++kc)
                bw[kc] = *(const f16x8*)&wp_h[wrow * 128 + kc * 32 + 8 * lg];
        } else {
#pragma unroll
            for (int kc = 0; kc < 4; ++kc)
                bw[kc] = cvt8(&wp_f[wrow * 128 + kc * 32 + 8 * lg]);
        }
        f32x4 acc = {0.f, 0.f, 0.f, 0.f};
#pragma unroll
        for (int kc = 0; kc < 4; ++kc) acc = MFMA16(aa[kc], bw[kc], acc);

        const float bc = bias[wrow];
#pragma unroll
        for (int reg = 0; reg < 4; ++reg) {
            const int n = r0 + 4 * lg + reg;
            if (n < 49) ob[n * 128 + ct * 16 + lr] = acc[reg] + bc;
        }
    }
}

extern "C" void kernel_launch(void* const* d_in, const int* in_sizes, int n_in,
                              void* d_out, int out_size, void* d_ws, size_t ws_size,
                              hipStream_t stream) {
    const float* x = (const float*)d_in[0];
    const float* mask = (const float*)d_in[1];
    const float* wq = (const float*)d_in[2];
    const float* wp = (const float*)d_in[3];
    const float* bp = (const float*)d_in[4];
    float* out = (float*)d_out;

    const size_t need_split = (size_t)(65536 + 3 * QKV_ELEMS) * sizeof(f16);
    const size_t need_wb = (size_t)(49152 + 16384) * sizeof(f16);

    if (ws_size >= need_split && d_ws != nullptr) {
        f16* wsh = (f16*)d_ws;
        f16* wq_h = wsh;
        f16* wp_h = wsh + 49152;
        f16* qws = wsh + 65536;
        f16* kws = qws + QKV_ELEMS;
        f16* vws = kws + QKV_ELEMS;
        cvt_weights<<<192, 256, 0, stream>>>(wq, wp, wsh);
        qkv_gemm<<<512, 512, 0, stream>>>(x, wq_h, qws, kws, vws);
        attn_proj<<<NWIN, 256, 0, stream>>>(qws, kws, vws, mask, wp_h, bp, out);
    } else if (ws_size >= need_wb && d_ws != nullptr) {
        f16* wsh = (f16*)d_ws;
        cvt_weights<<<192, 256, 0, stream>>>(wq, wp, wsh);
        fused_wattn<true><<<4096, 256, 0, stream>>>(x, mask, wq, wp, wsh, wsh + 49152, bp, out);
    } else {
        fused_wattn<false><<<4096, 256, 0, stream>>>(x, mask, wq, wp, nullptr, nullptr, bp, out);
    }
}

// Round 8
// 117.394 us; speedup vs baseline: 2.2188x; 1.8886x over previous
//
#include <hip/hip_runtime.h>
#include <hip/hip_bf16.h>

typedef _Float16 f16;
typedef __attribute__((ext_vector_type(8))) _Float16 f16x8;
typedef __attribute__((ext_vector_type(4))) _Float16 f16x4;
typedef __attribute__((ext_vector_type(4))) float f32x4;

#define MFMA16(a, b, c) __builtin_amdgcn_mfma_f32_16x16x32_f16((a), (b), (c), 0, 0, 0)

#define NWIN 4096
#define WPB 16  // windows per block; grid = 256 = exactly 1 block/CU

// ---------------------------------------------------------------------------
// Weight pre-convert: f32 -> f16 into workspace (wq 49152 + wp 16384 elems).
// ---------------------------------------------------------------------------
__global__ void cvt_weights(const float* __restrict__ wq,
                            const float* __restrict__ wp,
                            f16* __restrict__ o) {
    int i = blockIdx.x * blockDim.x + threadIdx.x;
    if (i < 49152) o[i] = (f16)wq[i];
    if (i < 16384) o[49152 + i] = (f16)wp[i];
}

__device__ inline f16x8 cvt8(const float* p) {
    float4 u0 = *(const float4*)p;
    float4 u1 = *(const float4*)(p + 4);
    f16x8 t;
    t[0] = (f16)u0.x; t[1] = (f16)u0.y; t[2] = (f16)u0.z; t[3] = (f16)u0.w;
    t[4] = (f16)u1.x; t[5] = (f16)u1.y; t[6] = (f16)u1.z; t[7] = (f16)u1.w;
    return t;
}

// ---------------------------------------------------------------------------
// Fully fused kernel: 256 blocks x 512 threads (8 waves), 16 windows each.
// Per window: A) QKV GEMM -> LDS (weights register-resident across all 16
// windows), B) attention (wave = M-tile x head-pair), C) out-projection
// (wave = one 16-col ct, wp tile register-resident). HBM traffic = x + out
// + weights only (~206 MB). LDS 101KB -> 1 block/CU.
// ---------------------------------------------------------------------------
__global__ __launch_bounds__(512, 2)
void fused_all(const float* __restrict__ x, const float* __restrict__ mask,
               const f16* __restrict__ wq_h, const f16* __restrict__ wp_h,
               const float* __restrict__ bias, float* __restrict__ out) {
    __shared__ f16 xb[2][64 * 128];  // x stage, double-buffered (32KB)
    __shared__ f16 qlds[64 * 128];   // Q rows, swizzled; reused as att buffer (16KB)
    __shared__ f16 klds[64 * 128];   // K rows, swizzled (16KB)
    __shared__ f16 vlds[128 * 64];   // V^T, swizzled (16KB)
    __shared__ f16 tscr[8][320];     // per-wave transpose scratch (5KB)
    __shared__ f16 scr[8][1024];     // per-wave P scratch (16KB)

    const int tid = threadIdx.x;
    const int wave = tid >> 6;
    const int lane = tid & 63;
    const int lg = lane >> 4;
    const int lr = lane & 15;
    const int w0 = blockIdx.x * WPB;

    // transpose-read lane mapping (verified r4 math)
    const int rdl = lane >> 2;
    const int ra = lane & 3;
    const int rg = 4 * (ra ^ ((rdl >> 2) & 3));

    // attention role: wave = (M-tile amt, head-pair ahh -> heads 2ahh,2ahh+1)
    const int amt = wave & 3;
    const int ahh = wave >> 2;
    const int ar0 = amt * 16;

    // ---- persistent register weights ----
    f16x8 bw[3][4];  // qkv ct = {wave, wave+8, wave+16}
#pragma unroll
    for (int j = 0; j < 3; ++j)
#pragma unroll
        for (int kc = 0; kc < 4; ++kc)
            bw[j][kc] = *(const f16x8*)&wq_h[((wave + 8 * j) * 16 + lr) * 128 + kc * 32 + 8 * lg];
    f16x8 wpr[4];    // proj ct = wave
#pragma unroll
    for (int kc = 0; kc < 4; ++kc)
        wpr[kc] = *(const f16x8*)&wp_h[(wave * 16 + lr) * 128 + kc * 32 + 8 * lg];
    const float bc = bias[wave * 16 + lr];

    auto stage = [&](int w, int p) {
        const float* xw = x + (size_t)w * (49 * 128);
        for (int i = tid; i < 2048; i += 512) {
            const int row = i >> 5;
            const int c4 = (i & 31) << 2;
            float4 v = {0.f, 0.f, 0.f, 0.f};
            if (row < 49) v = ((const float4*)xw)[i];
            f16x4 t;
            t[0] = (f16)v.x; t[1] = (f16)v.y; t[2] = (f16)v.z; t[3] = (f16)v.w;
            *(f16x4*)&xb[p][row * 128 + (c4 ^ ((row & 7) << 3))] = t;
        }
    };

    stage(w0, 0);
    __syncthreads();

    const float sc = 0.17677669529663687f;  // 32^-0.5

    for (int wi = 0; wi < WPB; ++wi) {
        const int w = w0 + wi;
        const int cur = wi & 1;
        if (wi < WPB - 1) stage(w + 1, cur ^ 1);

        // mask prefetch for phase B (rows ar0+4lg+reg, cols nt*16+lr)
        const float* mw = mask + (size_t)(w & 63) * (49 * 49);
        float mv[4][4];
#pragma unroll
        for (int reg = 0; reg < 4; ++reg) {
            const int n = ar0 + 4 * lg + reg;
#pragma unroll
            for (int nt = 0; nt < 4; ++nt) {
                const int col = nt * 16 + lr;
                mv[reg][nt] = (n < 49 && col < 49) ? mw[n * 49 + col] : 0.f;
            }
        }

        // ================= Phase A: QKV -> LDS =================
#pragma unroll
        for (int mt = 0; mt < 4; ++mt) {
            const int nb = mt * 16;
            f16x8 a[4];
#pragma unroll
            for (int kc = 0; kc < 4; ++kc)
                a[kc] = *(const f16x8*)&xb[cur][(nb + lr) * 128 + ((kc * 32 + 8 * lg) ^ ((lr & 7) << 3))];

#pragma unroll
            for (int j = 0; j < 3; ++j) {
                __builtin_amdgcn_s_setprio(1);
                f32x4 acc = {0.f, 0.f, 0.f, 0.f};
#pragma unroll
                for (int kc = 0; kc < 4; ++kc) acc = MFMA16(a[kc], bw[j][kc], acc);
                __builtin_amdgcn_s_setprio(0);

                if (j < 2) {
                    // D-frag -> row-major via tscr (verified r4 math)
#pragma unroll
                    for (int reg = 0; reg < 4; ++reg)
                        tscr[wave][(4 * lg + reg) * 20 + (lr ^ (4 * lg))] = (f16)acc[reg];
                    f16x4 seg = *(const f16x4*)&tscr[wave][rdl * 20 + rg];
                    const int n = nb + rdl;
                    const int c = wave * 16 + 4 * ra;  // local col for Q AND K
                    f16* dst = (j == 0) ? qlds : klds;
                    *(f16x4*)&dst[n * 128 + (c ^ ((n & 7) << 3))] = seg;
                } else {
                    // V: transpose to [vch][n], swizzled (verified r4 math)
#pragma unroll
                    for (int reg = 0; reg < 4; ++reg)
                        tscr[wave][lr * 20 + ((4 * lg + reg) ^ (lr & 12))] = (f16)acc[reg];
                    f16x4 seg = *(const f16x4*)&tscr[wave][rdl * 20 + rg];
                    const int vch = wave * 16 + rdl;
                    const int c = nb + 4 * ra;
                    *(f16x4*)&vlds[vch * 64 + (c ^ ((vch & 7) << 3))] = seg;
                }
            }
        }
        __syncthreads();  // Q/K/V visible to all waves

        // ================= Phase B: attention =================
        f16* ps = scr[wave];
        f32x4 oacc[2][2];
#pragma unroll
        for (int hi = 0; hi < 2; ++hi) {
            const int h = 2 * ahh + hi;
            const int arow = ar0 + lr;
            f16x8 aq = *(const f16x8*)&qlds[arow * 128 + ((h * 32 + 8 * lg) ^ ((arow & 7) << 3))];

            f16x8 bk[4];
#pragma unroll
            for (int nt = 0; nt < 4; ++nt) {
                const int krow = nt * 16 + lr;
                bk[nt] = *(const f16x8*)&klds[krow * 128 + ((h * 32 + 8 * lg) ^ ((krow & 7) << 3))];
            }
            f16x8 bv[2][2];
#pragma unroll
            for (int nt = 0; nt < 2; ++nt)
#pragma unroll
                for (int kc = 0; kc < 2; ++kc) {
                    const int vrow = h * 32 + nt * 16 + lr;
                    bv[nt][kc] = *(const f16x8*)&vlds[vrow * 64 + ((kc * 32 + 8 * lg) ^ ((vrow & 7) << 3))];
                }

            __builtin_amdgcn_s_setprio(1);
            f32x4 s[4];
#pragma unroll
            for (int nt = 0; nt < 4; ++nt) {
                f32x4 z = {0.f, 0.f, 0.f, 0.f};
                s[nt] = MFMA16(aq, bk[nt], z);
            }
            __builtin_amdgcn_s_setprio(0);

            // unnormalized softmax -> ps; row-sums local (r7-verified)
            float lsum[4];
#pragma unroll
            for (int reg = 0; reg < 4; ++reg) {
                const int row = 4 * lg + reg;
                float sum = 0.f;
#pragma unroll
                for (int nt = 0; nt < 4; ++nt) {
                    const int col = nt * 16 + lr;
                    float e = (col < 49) ? __expf(s[nt][reg] * sc + mv[reg][nt]) : 0.f;
                    sum += e;
                    ps[row * 64 + (col ^ ((row & 7) << 3))] = (f16)e;
                }
                lsum[reg] = sum;
            }

            f16x8 ap[2];
#pragma unroll
            for (int kc = 0; kc < 2; ++kc)
                ap[kc] = *(const f16x8*)&ps[lr * 64 + ((kc * 32 + 8 * lg) ^ ((lr & 7) << 3))];
            __builtin_amdgcn_s_setprio(1);
            f32x4 acc0 = {0.f, 0.f, 0.f, 0.f};
            f32x4 acc1 = {0.f, 0.f, 0.f, 0.f};
#pragma unroll
            for (int kc = 0; kc < 2; ++kc) {
                acc0 = MFMA16(ap[kc], bv[0][kc], acc0);
                acc1 = MFMA16(ap[kc], bv[1][kc], acc1);
            }
            __builtin_amdgcn_s_setprio(0);

#pragma unroll
            for (int reg = 0; reg < 4; ++reg) {
                float sum = lsum[reg];
                for (int d = 1; d < 16; d <<= 1) sum += __shfl_xor(sum, d, 64);
                const float inv = __fdividef(1.f, sum);
                acc0[reg] *= inv;
                acc1[reg] *= inv;
            }
            oacc[hi][0] = acc0;
            oacc[hi][1] = acc1;
        }

        // att -> qlds (each wave overwrites exactly the region it read as Q)
#pragma unroll
        for (int hi = 0; hi < 2; ++hi)
#pragma unroll
            for (int nt = 0; nt < 2; ++nt)
#pragma unroll
                for (int reg = 0; reg < 4; ++reg) {
                    const int n = ar0 + 4 * lg + reg;
                    const int c = (2 * ahh + hi) * 32 + nt * 16 + lr;
                    qlds[n * 128 + (c ^ ((n & 7) << 3))] = (f16)oacc[hi][nt][reg];
                }
        __syncthreads();  // att complete

        // ================= Phase C: out projection =================
        float* ob = out + (size_t)w * (49 * 128);
#pragma unroll
        for (int mt = 0; mt < 4; ++mt) {
            const int arow = mt * 16 + lr;
            f16x8 aa[4];
#pragma unroll
            for (int kc = 0; kc < 4; ++kc)
                aa[kc] = *(const f16x8*)&qlds[arow * 128 + ((kc * 32 + 8 * lg) ^ ((arow & 7) << 3))];
            __builtin_amdgcn_s_setprio(1);
            f32x4 acc = {0.f, 0.f, 0.f, 0.f};
#pragma unroll
            for (int kc = 0; kc < 4; ++kc) acc = MFMA16(aa[kc], wpr[kc], acc);
            __builtin_amdgcn_s_setprio(0);

#pragma unroll
            for (int reg = 0; reg < 4; ++reg) {
                const int n = mt * 16 + 4 * lg + reg;
                if (n < 49) ob[n * 128 + wave * 16 + lr] = acc[reg] + bc;
            }
        }
        __syncthreads();  // qlds/klds/vlds free for next window's phase A
    }
}

// ---------------------------------------------------------------------------
// Fallback: fused per-window kernel (no workspace needed).
// ---------------------------------------------------------------------------
template <bool WB>
__global__ __launch_bounds__(256, 4)
void fused_wattn(const float* __restrict__ x, const float* __restrict__ mask,
                 const float* __restrict__ wq_f, const float* __restrict__ wp_f,
                 const f16* __restrict__ wq_h, const f16* __restrict__ wp_h,
                 const float* __restrict__ bias, float* __restrict__ out) {
    __shared__ f16 ks[64 * 128];
    __shared__ f16 vt[128 * 64];
    __shared__ f16 scr[4][1024];

    const int b = blockIdx.x;
    const int wid = b & 63;
    const int tid = threadIdx.x;
    const int wave = tid >> 6;
    const int lane = tid & 63;
    const int lg = lane >> 4;
    const int lr = lane & 15;
    const int r0 = wave * 16;
    f16* ps = scr[wave];

    f16x8 a[4];
    {
        const int xrow = r0 + lr;
        if (xrow < 49) {
            const float* xp = x + ((size_t)b * 49 + xrow) * 128 + 8 * lg;
#pragma unroll
            for (int kc = 0; kc < 4; ++kc) a[kc] = cvt8(xp + kc * 32);
        } else {
            f16x8 z = {0, 0, 0, 0, 0, 0, 0, 0};
#pragma unroll
            for (int kc = 0; kc < 4; ++kc) a[kc] = z;
        }
    }

    float mv[4][4];
#pragma unroll
    for (int reg = 0; reg < 4; ++reg) {
        const int n = r0 + 4 * lg + reg;
#pragma unroll
        for (int nt = 0; nt < 4; ++nt) {
            const int col = nt * 16 + lr;
            mv[reg][nt] = (n < 49 && col < 49) ? mask[((size_t)wid * 49 + n) * 49 + col] : 0.f;
        }
    }

    f16x4 qd[8];
#pragma unroll
    for (int ct = 0; ct < 24; ++ct) {
        const int wrow = ct * 16 + lr;
        f16x8 bw[4];
        if (WB) {
#pragma unroll
            for (int kc = 0; kc < 4; ++kc)
                bw[kc] = *(const f16x8*)&wq_h[wrow * 128 + kc * 32 + 8 * lg];
        } else {
#pragma unroll
            for (int kc = 0; kc < 4; ++kc)
                bw[kc] = cvt8(&wq_f[wrow * 128 + kc * 32 + 8 * lg]);
        }
        f32x4 acc = {0.f, 0.f, 0.f, 0.f};
#pragma unroll
        for (int kc = 0; kc < 4; ++kc) acc = MFMA16(a[kc], bw[kc], acc);

        if (ct < 8) {
            f16x4 q;
#pragma unroll
            for (int reg = 0; reg < 4; ++reg) q[reg] = (f16)acc[reg];
            qd[ct] = q;
        } else if (ct < 16) {
#pragma unroll
            for (int reg = 0; reg < 4; ++reg) {
                const int n = r0 + 4 * lg + reg;
                const int c = wrow - 128;
                ks[n * 128 + (c ^ ((n & 7) << 3))] = (f16)acc[reg];
            }
        } else {
#pragma unroll
            for (int reg = 0; reg < 4; ++reg) {
                const int n = r0 + 4 * lg + reg;
                const int dch = wrow - 256;
                vt[dch * 64 + (n ^ ((dch & 7) << 3))] = (f16)acc[reg];
            }
        }
    }
    __syncthreads();

    const float sc = 0.17677669529663687f;
    f32x4 oacc[4][2];

#pragma unroll
    for (int h = 0; h < 4; ++h) {
#pragma unroll
        for (int c2 = 0; c2 < 2; ++c2)
#pragma unroll
            for (int reg = 0; reg < 4; ++reg) {
                const int row = 4 * lg + reg;
                const int col = c2 * 16 + lr;
                ps[row * 32 + (col ^ ((row & 3) << 3))] = qd[2 * h + c2][reg];
            }
        f16x8 aq = *(const f16x8*)&ps[lr * 32 + ((8 * lg) ^ ((lr & 3) << 3))];

        f32x4 s[4];
#pragma unroll
        for (int nt = 0; nt < 4; ++nt) {
            const int krow = nt * 16 + lr;
            f16x8 bk = *(const f16x8*)&ks[krow * 128 + ((h * 32 + 8 * lg) ^ ((krow & 7) << 3))];
            f32x4 z = {0.f, 0.f, 0.f, 0.f};
            s[nt] = MFMA16(aq, bk, z);
        }

#pragma unroll
        for (int reg = 0; reg < 4; ++reg) {
            float vals[4];
            float sum = 0.f;
#pragma unroll
            for (int nt = 0; nt < 4; ++nt) {
                const int col = nt * 16 + lr;
                float e = (col < 49) ? __expf(s[nt][reg] * sc + mv[reg][nt]) : 0.f;
                vals[nt] = e;
                sum += e;
            }
            for (int d = 1; d < 16; d <<= 1) sum += __shfl_xor(sum, d, 64);
            const float inv = __fdividef(1.f, sum);
            const int row = 4 * lg + reg;
#pragma unroll
            for (int nt = 0; nt < 4; ++nt) {
                const int col = nt * 16 + lr;
                ps[row * 64 + (col ^ ((row & 7) << 3))] = (f16)(vals[nt] * inv);
            }
        }

        f16x8 ap[2];
#pragma unroll
        for (int kc = 0; kc < 2; ++kc)
            ap[kc] = *(const f16x8*)&ps[lr * 64 + ((kc * 32 + 8 * lg) ^ ((lr & 7) << 3))];
#pragma unroll
        for (int nt = 0; nt < 2; ++nt) {
            const int vrow = h * 32 + nt * 16 + lr;
            f32x4 acc = {0.f, 0.f, 0.f, 0.f};
#pragma unroll
            for (int kc = 0; kc < 2; ++kc) {
                f16x8 bv = *(const f16x8*)&vt[vrow * 64 + ((kc * 32 + 8 * lg) ^ ((vrow & 7) << 3))];
                acc = MFMA16(ap[kc], bv, acc);
            }
            oacc[h][nt] = acc;
        }
    }

    f16x8 aa[4];
#pragma unroll
    for (int pass = 0; pass < 2; ++pass) {
#pragma unroll
        for (int h2 = 0; h2 < 2; ++h2)
#pragma unroll
            for (int nt = 0; nt < 2; ++nt)
#pragma unroll
                for (int reg = 0; reg < 4; ++reg) {
                    const int row = 4 * lg + reg;
                    const int col = h2 * 32 + nt * 16 + lr;
                    ps[row * 64 + (col ^ ((row & 7) << 3))] = (f16)oacc[pass * 2 + h2][nt][reg];
                }
#pragma unroll
        for (int kcg = 0; kcg < 2; ++kcg)
            aa[pass * 2 + kcg] = *(const f16x8*)&ps[lr * 64 + ((kcg * 32 + 8 * lg) ^ ((lr & 7) << 3))];
    }

    float* ob = out + (size_t)b * (49 * 128);
#pragma unroll
    for (int ct = 0; ct < 8; ++ct) {
        const int wrow = ct * 16 + lr;
        f16x8 bw[4];
        if (WB) {
#pragma unroll
            for (int kc = 0; kc < 4; ++kc)
                bw[kc] = *(const f16x8*)&wq_h[wrow * 128 + kc * 32 + 8 * lg];
        } else {
#pragma unroll
            for (int kc = 0; kc < 4; ++kc)
                bw[kc] = cvt8(&wp_f[wrow * 128 + kc * 32 + 8 * lg]);
        }
        f32x4 acc = {0.f, 0.f, 0.f, 0.f};
#pragma unroll
        for (int kc = 0; kc < 4; ++kc) acc = MFMA16(aa[kc], bw[kc], acc);

        const float bc = bias[wrow];
#pragma unroll
        for (int reg = 0; reg < 4; ++reg) {
            const int n = r0 + 4 * lg + reg;
            if (n < 49) ob[n * 128 + ct * 16 + lr] = acc[reg] + bc;
        }
    }
}

extern "C" void kernel_launch(void* const* d_in, const int* in_sizes, int n_in,
                              void* d_out, int out_size, void* d_ws, size_t ws_size,
                              hipStream_t stream) {
    const float* x = (const float*)d_in[0];
    const float* mask = (const float*)d_in[1];
    const float* wq = (const float*)d_in[2];
    const float* wp = (const float*)d_in[3];
    const float* bp = (const float*)d_in[4];
    float* out = (float*)d_out;

    const size_t need_wb = (size_t)(49152 + 16384) * sizeof(f16);

    if (ws_size >= need_wb && d_ws != nullptr) {
        f16* wsh = (f16*)d_ws;
        cvt_weights<<<192, 256, 0, stream>>>(wq, wp, wsh);
        fused_all<<<NWIN / WPB, 512, 0, stream>>>(x, mask, wsh, wsh + 49152, bp, out);
    } else {
        fused_wattn<false><<<4096, 256, 0, stream>>>(x, mask, wq, wp, nullptr, nullptr, bp, out);
    }
}